// Round 1
// baseline (419.733 us; speedup 1.0000x reference)
//
#include <hip/hip_runtime.h>

#define HSZ 50
#define TSZ 512

// sigmoid(x) = 1/(1+exp(-x)); robust at extremes (exp->inf => 0, exp->0 => 1)
__device__ __forceinline__ float fast_sig(float x) {
    return __builtin_amdgcn_rcpf(1.0f + __expf(-x));
}
// tanh(x) = 1 - 2/(exp(2x)+1); robust at extremes (exp->inf => 1, exp->0 => -1)
__device__ __forceinline__ float fast_tanh(float x) {
    return fmaf(-2.0f, __builtin_amdgcn_rcpf(1.0f + __expf(2.0f * x)), 1.0f);
}

// One wave (64 lanes) per batch element. Lane j<50 owns hidden unit j and its
// four gate rows of W_hh (kept entirely in VGPRs: 4*25 float2 = 200 regs).
// The T-loop is wave-synchronous: h is broadcast through a private per-wave
// LDS line (1 ds_write + 13 broadcast ds_read_b128 per step), no barriers.
__global__ __launch_bounds__(256, 2)
void lstm_fused(const float* __restrict__ x,
                const float* __restrict__ W_ih,
                const float* __restrict__ W_hh,
                const float* __restrict__ b_ih,
                const float* __restrict__ b_hh,
                const float* __restrict__ W_lin,
                const float* __restrict__ b_lin,
                float* __restrict__ out)
{
    __shared__ float xs[4 * TSZ];     // staged x for this block's 4 batches
    __shared__ float hbuf[4][64];     // per-wave h broadcast line (16B aligned)

    const int tid = threadIdx.x;
    const int w   = tid >> 6;         // wave id within block (0..3)
    const int j   = tid & 63;         // lane id
    const int b   = blockIdx.x * 4 + w;

    // Coalesced stage of x[b0..b0+3][0..T): block-flat layout matches global.
    const float* xg = x + (size_t)blockIdx.x * 4 * TSZ;
    for (int idx = tid; idx < 4 * TSZ; idx += 256)
        xs[idx] = xg[idx];

    const bool active = (j < HSZ);
    const int  jj     = active ? j : 0;

    // Per-lane weights in registers. Inactive lanes get zeros -> they compute
    // h == 0 harmlessly every step (i=f=o=0.5, g=0 -> c=0, h=0).
    float2 w2[4][25];
    float  wih[4], bias[4];
#pragma unroll
    for (int g = 0; g < 4; ++g) {
        const int row = g * HSZ + jj;             // PyTorch gate order i,f,g,o
        const float2* rp = (const float2*)(W_hh + row * HSZ);  // 200B rows, 8B aligned
#pragma unroll
        for (int p = 0; p < 25; ++p) {
            float2 v = rp[p];
            w2[g][p].x = active ? v.x : 0.0f;
            w2[g][p].y = active ? v.y : 0.0f;
        }
        wih[g]  = active ? W_ih[row] : 0.0f;
        bias[g] = active ? (b_ih[row] + b_hh[row]) : 0.0f;
    }

    hbuf[w][j] = 0.0f;                // h0 = 0 (also zeros pad entries 50..63)
    float h = 0.0f, c = 0.0f;
    __syncthreads();                  // xs ready

    const float4* hb4 = (const float4*)(&hbuf[w][0]);
    const float*  xw  = &xs[w * TSZ];

    for (int t = 0; t < TSZ; ++t) {
        const float xv = xw[t];       // wave-uniform LDS broadcast
        float ax[4], ay[4];           // two partial accumulators per gate (ILP)
#pragma unroll
        for (int g = 0; g < 4; ++g) { ax[g] = fmaf(xv, wih[g], bias[g]); ay[g] = 0.0f; }

        // gates[g] += sum_k h[k] * W_hh[g*50+j][k], h broadcast from LDS.
#pragma unroll
        for (int q = 0; q < 13; ++q) {            // 13 float4 covers k=0..49 (+pad)
            const float4 hv = hb4[q];
#pragma unroll
            for (int g = 0; g < 4; ++g) {
                ax[g] = fmaf(hv.x, w2[g][2*q].x, ax[g]);
                ay[g] = fmaf(hv.y, w2[g][2*q].y, ay[g]);
            }
            if (q < 12) {                          // pair 25 doesn't exist (k=50,51 pad)
#pragma unroll
                for (int g = 0; g < 4; ++g) {
                    ax[g] = fmaf(hv.z, w2[g][2*q+1].x, ax[g]);
                    ay[g] = fmaf(hv.w, w2[g][2*q+1].y, ay[g]);
                }
            }
        }

        const float gi = fast_sig (ax[0] + ay[0]);
        const float gf = fast_sig (ax[1] + ay[1]);
        const float gg = fast_tanh(ax[2] + ay[2]);
        const float go = fast_sig (ax[3] + ay[3]);
        c = fmaf(gf, c, gi * gg);
        h = go * fast_tanh(c);
        hbuf[w][j] = h;               // in-order per-wave LDS: next iter sees it
    }

    // out[b] = dot(h_T, W_lin) + b_lin  (inactive lanes hold h==0, wl==0)
    const float wl = active ? W_lin[j] : 0.0f;
    float p = h * wl;
#pragma unroll
    for (int off = 32; off > 0; off >>= 1)
        p += __shfl_down(p, off, 64);
    if (j == 0) out[b] = p + b_lin[0];
}

extern "C" void kernel_launch(void* const* d_in, const int* in_sizes, int n_in,
                              void* d_out, int out_size, void* d_ws, size_t ws_size,
                              hipStream_t stream) {
    const float* x     = (const float*)d_in[0];
    const float* W_ih  = (const float*)d_in[1];
    const float* W_hh  = (const float*)d_in[2];
    const float* b_ih  = (const float*)d_in[3];
    const float* b_hh  = (const float*)d_in[4];
    const float* W_lin = (const float*)d_in[5];
    const float* b_lin = (const float*)d_in[6];
    float* outp = (float*)d_out;

    const int B = in_sizes[0] / TSZ;   // 2048 for this problem (divisible by 4)
    hipLaunchKernelGGL(lstm_fused, dim3(B / 4), dim3(256), 0, stream,
                       x, W_ih, W_hh, b_ih, b_hh, W_lin, b_lin, outp);
}